// Round 7
// baseline (331.854 us; speedup 1.0000x reference)
//
#include <hip/hip_runtime.h>
#include <math.h>

// Sizes (fixed by the reference)
#define NB 1024
#define TT 5
#define NN 6
#define DD 192
#define EE 12
#define MM 12
#define LL 512
#define OO 6
#define GOUT 768              // GRU GEMM N: [r|z|inn|hn]
#define KPAD 224              // GRU K: 12 + 192 + 20 pad
#define NKT (KPAD/32)         // 7 k-tiles
#define NJT (GOUT/16)         // 48 n-tiles

#define ROWS 30               // (t,n) rows per batch
#define HP 196                // sh_h pitch (floats)
#define LNKPU 20              // linkA pitch (uints) = 40 fp16 = 80 B
#define GRUPU 116             // gruA pitch (uints) = 232 fp16 = 464 B

typedef __attribute__((ext_vector_type(8))) _Float16 f16x8;
typedef __attribute__((ext_vector_type(4))) float f32x4;

__device__ __forceinline__ float sigmoidf_(float x) { return 1.f / (1.f + __expf(-x)); }
__device__ __forceinline__ float dot4(float4 a, float4 b) {
  return a.x*b.x + a.y*b.y + a.z*b.z + a.w*b.w;
}
__device__ __forceinline__ unsigned short f2h(float f) {
  _Float16 h = (_Float16)f;
  unsigned short s; __builtin_memcpy(&s, &h, 2); return s;
}
__device__ __forceinline__ unsigned int pack2h(float a, float b) {
  return (unsigned int)f2h(a) | ((unsigned int)f2h(b) << 16);
}

// ---------------------------------------------------------------- k_pack (GRU W, fp16)
__global__ void k_pack(const float* __restrict__ Wih, const float* __restrict__ Whh,
                       const float* __restrict__ bih, const float* __restrict__ bhh,
                       unsigned short* __restrict__ Bh, float* __restrict__ bias768)
{
  int idx = blockIdx.x * 256 + threadIdx.x;
  if (idx < GOUT) {
    int c = idx; float b;
    if (c < 384)      b = bih[c] + bhh[c];
    else if (c < 576) b = bih[c];
    else              b = bhh[c - 192];
    bias768[c] = b;
  }
  if (idx >= NJT*NKT*512) return;
  int e = idx & 7, l = (idx >> 3) & 63;
  int rem = idx >> 9, kt = rem % NKT, j = rem / NKT;
  int k = kt*32 + ((l >> 4) << 3) + e;
  int c = j*16 + (l & 15);
  float v = 0.f;
  if (k < 204) {
    if (c < 384)      v = (k < 12) ? Wih[c*MM + k] : Whh[(size_t)c*DD + (k-12)];
    else if (c < 576) v = (k < 12) ? Wih[c*MM + k] : 0.f;
    else              v = (k < 12) ? 0.f : Whh[(size_t)(c-192)*DD + (k-12)];
  }
  Bh[idx] = f2h(v);
}

// ---------------------------------------------------------------- k_pack_link (fp16)
__global__ void k_pack_link(const float* __restrict__ w1,
                            unsigned short* __restrict__ BLh)
{
  int idx = blockIdx.x * 256 + threadIdx.x;
  if (idx >= 32*512) return;
  int e = idx & 7, l = (idx >> 3) & 63, nt = idx >> 9;
  int k = ((l >> 4) << 3) + e;
  int c = nt*16 + (l & 15);
  float v = (k < 12) ? w1[c*EE + k] : 0.f;
  BLh[idx] = f2h(v);
}

// ---------------------------------------------------------------- k_fused
// One WG per batch b. Entire 2-layer network batch-local in LDS:
// link (MFMA) -> adj -> messages -> msum -> GRU (MFMA) -> [x2] -> conv.
__global__ __launch_bounds__(256, 2)
void k_fused(const float* __restrict__ nr, const float* __restrict__ pos,
             const int* __restrict__ attmat,
             const unsigned short* __restrict__ BLh,
             const float* __restrict__ lb1, const float* __restrict__ lw2,
             const float* __restrict__ lb2,
             const float* __restrict__ msg_Wh, const float* __restrict__ msg_We,
             const float* __restrict__ msg_b,
             const unsigned short* __restrict__ Bh, const float* __restrict__ bias768,
             const float* __restrict__ conv1_w, const float* __restrict__ conv1_b,
             const float* __restrict__ conv2_w, const float* __restrict__ conv2_b,
             float* __restrict__ out)
{
  __shared__ __align__(16) float sh_h[ROWS][HP];        // 23520 B, fp32 node state
  __shared__ __align__(16) float sh_e[180][EE];         // 8640 B, original edge feats
  __shared__ __align__(16) float sh_m[180][MM];         // 8640 B, messages
  __shared__ __align__(16) float sh_mh[ROWS][MM];       // 1440 B
  __shared__ __align__(16) float sh_msum[ROWS][MM];     // 1440 B
  __shared__ float sh_adj[192];                         // 768 B
  __shared__ __align__(16) unsigned int shA[192*LNKPU]; // 15360 B (linkA | gruA union)
  __shared__ float red[4][OO];

  const int tid = threadIdx.x;
  const int b = blockIdx.x;
  const int lane = tid & 63, wid = tid >> 6;
  const int col = lane & 15, quad = lane >> 4;

  // ---- Phase 0: h and edge features ----
  for (int i = tid; i < TT*DD*NN; i += 256) {
    int t = i / (DD*NN), rem = i % (DD*NN);
    int d = rem / NN, n = rem % NN;
    sh_h[t*NN + n][d] = nr[(size_t)b*TT*DD*NN + i];     // coalesced
  }
  for (int idx = tid; idx < 180*EE; idx += 256) {
    int e = idx / EE, c = idx % EE;
    int t = e / 36, ij = e % 36;
    int i_ = ij / NN, j_ = ij % NN;
    bool msk = (attmat[(b*TT + t)*36 + ij] == 1) && (i_ != j_);
    int srcn = (c < 6) ? i_ : j_;
    int cc   = (c < 6) ? c  : c - 6;
    sh_e[e][c] = msk ? pos[((b*TT + t)*NN + srcn)*6 + cc] : 0.f;
  }
  __syncthreads();

  for (int L = 0; L < 2; ++L) {
    // ---- link A staging: 192 rows (180 real) x 32 k, fp16 ----
    for (int idx = tid; idx < 192*16; idx += 256) {
      int r = idx >> 4, p = idx & 15;
      float a0 = 0.f, a1 = 0.f;
      if (r < 180) {
        const float* src = (L == 0) ? &sh_e[r][0] : &sh_m[r][0];
        if (2*p   < 12) a0 = src[2*p];
        if (2*p+1 < 12) a1 = src[2*p+1];
      }
      shA[r*LNKPU + p] = pack2h(a0, a1);
    }
    __syncthreads();

    // ---- link MFMA: wave owns m-tiles {wid*3..+2}; fused relu->w2->sigmoid ----
    {
      f16x8 am[3];
      #pragma unroll
      for (int mtl = 0; mtl < 3; ++mtl)
        am[mtl] = *(const f16x8*)((const char*)shA
                    + ((wid*3 + mtl)*16 + col)*(LNKPU*4) + quad*16);
      float s[3][4];
      #pragma unroll
      for (int mtl = 0; mtl < 3; ++mtl)
        #pragma unroll
        for (int q = 0; q < 4; ++q) s[mtl][q] = 0.f;
      for (int nt = 0; nt < 32; ++nt) {
        f16x8 bh = *(const f16x8*)(BLh + nt*512 + lane*8);
        float b1v = lb1[nt*16 + col];
        float w2v = lw2[nt*16 + col];
        #pragma unroll
        for (int mtl = 0; mtl < 3; ++mtl) {
          f32x4 acc = (f32x4)0.f;
          acc = __builtin_amdgcn_mfma_f32_16x16x32_f16(am[mtl], bh, acc, 0, 0, 0);
          #pragma unroll
          for (int q = 0; q < 4; ++q)
            s[mtl][q] += w2v * fmaxf(acc[q] + b1v, 0.f);
        }
      }
      #pragma unroll
      for (int mtl = 0; mtl < 3; ++mtl)
        #pragma unroll
        for (int q = 0; q < 4; ++q) {
          float v = s[mtl][q];
          v += __shfl_xor(v, 1); v += __shfl_xor(v, 2);
          v += __shfl_xor(v, 4); v += __shfl_xor(v, 8);
          s[mtl][q] = v;
        }
      if (col == 0) {
        float b2 = lb2[0];
        #pragma unroll
        for (int mtl = 0; mtl < 3; ++mtl)
          #pragma unroll
          for (int q = 0; q < 4; ++q)
            sh_adj[wid*48 + mtl*16 + quad*4 + q] = sigmoidf_(s[mtl][q] + b2);
      }
    }
    __syncthreads();

    // ---- mh[r][o] = msg_b[o] + Wh[o,:] . h[r,:] ----
    for (int idx = tid; idx < ROWS*MM; idx += 256) {
      int r = idx / MM, o = idx % MM;
      const float4* wrow = (const float4*)(msg_Wh + (size_t)o*DD);
      const float4* hrow = (const float4*)&sh_h[r][0];
      float acc = msg_b[o];
      #pragma unroll 8
      for (int d4 = 0; d4 < DD/4; ++d4) acc += dot4(wrow[d4], hrow[d4]);
      sh_mh[r][o] = acc;
    }
    __syncthreads();

    // ---- m = adj * relu(mh_j + We.e) ----
    for (int idx = tid; idx < 180*MM; idx += 256) {
      int e = idx / MM, o = idx % MM;
      int t = e / 36, j_ = e % NN;
      const float4* we = (const float4*)(msg_We + o*EE);
      const float4* ev = (const float4*)&sh_e[e][0];
      float me = dot4(we[0],ev[0]) + dot4(we[1],ev[1]) + dot4(we[2],ev[2]);
      sh_m[e][o] = sh_adj[e] * fmaxf(sh_mh[t*NN + j_][o] + me, 0.f);
    }
    __syncthreads();

    // ---- msum[r=t*6+i][o] = sum_j m[t*36+i*6+j][o] ----
    for (int idx = tid; idx < ROWS*MM; idx += 256) {
      int r = idx / MM, o = idx % MM;
      int t = r / NN, i_ = r % NN;
      float s = 0.f;
      #pragma unroll
      for (int j = 0; j < NN; ++j) s += sh_m[t*36 + i_*NN + j][o];
      sh_msum[r][o] = s;
    }
    __syncthreads();

    // ---- GRU A staging: 32 rows x 224 k, fp16 (aliases linkA) ----
    for (int idx = tid; idx < 32*(KPAD/2); idx += 256) {
      int r = idx / (KPAD/2), kp = idx % (KPAD/2);
      int k0 = 2*kp, k1 = k0 + 1;
      float a0 = 0.f, a1 = 0.f;
      if (r < ROWS) {
        a0 = (k0 < 12) ? sh_msum[r][k0] : (k0 < 204 ? sh_h[r][k0-12] : 0.f);
        a1 = (k1 < 12) ? sh_msum[r][k1] : (k1 < 204 ? sh_h[r][k1-12] : 0.f);
      }
      shA[r*GRUPU + kp] = pack2h(a0, a1);
    }
    __syncthreads();

    // ---- GRU MFMA [32x224]x[224x768]; wave owns d-tiles {wid*3..+2} x 4 gates.
    // inn gate (g=2) B is zero for k>=12 -> only kt==0 contributes.
    {
      f32x4 acc[4][3][2];
      #pragma unroll
      for (int g = 0; g < 4; ++g)
        #pragma unroll
        for (int i = 0; i < 3; ++i)
          #pragma unroll
          for (int rt = 0; rt < 2; ++rt) acc[g][i][rt] = (f32x4)0.f;

      const char* ahb = (const char*)shA + col*(GRUPU*4) + quad*16;
      const int g_of[3] = {0, 1, 3};

      for (int kt = 0; kt < NKT; ++kt) {
        f16x8 ah0 = *(const f16x8*)(ahb + kt*64);
        f16x8 ah1 = *(const f16x8*)(ahb + 16*(GRUPU*4) + kt*64);
        f16x8 bf[9];
        #pragma unroll
        for (int gg = 0; gg < 3; ++gg)
          #pragma unroll
          for (int i = 0; i < 3; ++i) {
            const int j = g_of[gg]*12 + wid*3 + i;
            bf[gg*3+i] = *(const f16x8*)(Bh + (((size_t)(j*NKT + kt)) << 9) + lane*8);
          }
        #pragma unroll
        for (int gg = 0; gg < 3; ++gg)
          #pragma unroll
          for (int i = 0; i < 3; ++i) {
            const int g = g_of[gg];
            acc[g][i][0] = __builtin_amdgcn_mfma_f32_16x16x32_f16(ah0, bf[gg*3+i], acc[g][i][0], 0, 0, 0);
            acc[g][i][1] = __builtin_amdgcn_mfma_f32_16x16x32_f16(ah1, bf[gg*3+i], acc[g][i][1], 0, 0, 0);
          }
        if (kt == 0) {
          #pragma unroll
          for (int i = 0; i < 3; ++i) {
            const int j = 24 + wid*3 + i;
            f16x8 b2f = *(const f16x8*)(Bh + (((size_t)(j*NKT)) << 9) + lane*8);
            acc[2][i][0] = __builtin_amdgcn_mfma_f32_16x16x32_f16(ah0, b2f, acc[2][i][0], 0, 0, 0);
            acc[2][i][1] = __builtin_amdgcn_mfma_f32_16x16x32_f16(ah1, b2f, acc[2][i][1], 0, 0, 0);
          }
        }
      }

      // epilogue: gates in-register; h updated in LDS
      #pragma unroll
      for (int i = 0; i < 3; ++i) {
        const int d = (wid*3 + i)*16 + col;
        const float bR = bias768[d], bZ = bias768[192 + d];
        const float bI = bias768[384 + d], bH = bias768[576 + d];
        #pragma unroll
        for (int rt = 0; rt < 2; ++rt) {
          #pragma unroll
          for (int q = 0; q < 4; ++q) {
            const int grow = rt*16 + quad*4 + q;
            if (grow < ROWS) {
              float r_ = sigmoidf_(acc[0][i][rt][q] + bR);
              float z_ = sigmoidf_(acc[1][i][rt][q] + bZ);
              float n_ = tanhf(acc[2][i][rt][q] + bI + r_*(acc[3][i][rt][q] + bH));
              float hold = sh_h[grow][d];
              sh_h[grow][d] = (1.f - z_)*n_ + z_*hold;
            }
          }
        }
      }
    }
    __syncthreads();
  }

  // ---- conv: out[b,:] = conv2( relu( conv1(h) + b1 ) ) + b2 ----
  {
    float acco[OO];
    #pragma unroll
    for (int o = 0; o < OO; ++o) acco[o] = 0.f;
    #pragma unroll
    for (int o = 0; o < OO; ++o) {
      const float* wo = conv1_w + (size_t)o*DD*TT*NN;
      for (int u = tid; u < DD*TT*NN; u += 256)
        acco[o] += wo[u] * sh_h[u % ROWS][u / ROWS];
    }
    #pragma unroll
    for (int o = 0; o < OO; ++o) {
      float v = acco[o];
      v += __shfl_xor(v, 1);  v += __shfl_xor(v, 2);  v += __shfl_xor(v, 4);
      v += __shfl_xor(v, 8);  v += __shfl_xor(v, 16); v += __shfl_xor(v, 32);
      acco[o] = v;
    }
    if (lane == 0) {
      #pragma unroll
      for (int o = 0; o < OO; ++o) red[wid][o] = acco[o];
    }
    __syncthreads();
    if (tid == 0) {
      float y[OO];
      #pragma unroll
      for (int o = 0; o < OO; ++o) {
        float s = conv1_b[o] + red[0][o] + red[1][o] + red[2][o] + red[3][o];
        y[o] = fmaxf(s, 0.f);
      }
      #pragma unroll
      for (int q = 0; q < OO; ++q) {
        float s = conv2_b[q];
        #pragma unroll
        for (int o = 0; o < OO; ++o) s += conv2_w[q*OO + o] * y[o];
        out[b*OO + q] = s;
      }
    }
  }
}

// ---------------------------------------------------------------- launch
extern "C" void kernel_launch(void* const* d_in, const int* in_sizes, int n_in,
                              void* d_out, int out_size, void* d_ws, size_t ws_size,
                              hipStream_t stream) {
  const float* node_resnet = (const float*)d_in[0];
  const float* pos      = (const float*)d_in[1];
  const int*   attmat   = (const int*)  d_in[2];
  const float* link_w1  = (const float*)d_in[3];
  const float* link_b1  = (const float*)d_in[4];
  const float* link_w2  = (const float*)d_in[5];
  const float* link_b2  = (const float*)d_in[6];
  const float* msg_Wh   = (const float*)d_in[7];
  const float* msg_We   = (const float*)d_in[8];
  const float* msg_b    = (const float*)d_in[9];
  const float* gru_Wih  = (const float*)d_in[10];
  const float* gru_Whh  = (const float*)d_in[11];
  const float* gru_bih  = (const float*)d_in[12];
  const float* gru_bhh  = (const float*)d_in[13];
  const float* conv1_w  = (const float*)d_in[14];
  const float* conv1_b  = (const float*)d_in[15];
  const float* conv2_w  = (const float*)d_in[16];
  const float* conv2_b  = (const float*)d_in[17];
  float* out = (float*)d_out;

  // ws layout: bias768 | Bh(fp16) | BLh(fp16)   (~0.4 MB)
  float* bias = (float*)d_ws;
  unsigned short* Bh  = (unsigned short*)(bias + GOUT);
  unsigned short* BLh = Bh + (size_t)NJT*NKT*512;

  k_pack<<<(NJT*NKT*512 + 255)/256, 256, 0, stream>>>(gru_Wih, gru_Whh,
      gru_bih, gru_bhh, Bh, bias);
  k_pack_link<<<(32*512 + 255)/256, 256, 0, stream>>>(link_w1, BLh);
  k_fused<<<NB, 256, 0, stream>>>(node_resnet, pos, attmat,
      BLh, link_b1, link_w2, link_b2,
      msg_Wh, msg_We, msg_b,
      Bh, bias,
      conv1_w, conv1_b, conv2_w, conv2_b, out);
}

// Round 8
// 184.611 us; speedup vs baseline: 1.7976x; 1.7976x over previous
//
#include <hip/hip_runtime.h>
#include <math.h>

// Sizes (fixed by the reference)
#define NB 1024
#define TT 5
#define NN 6
#define DD 192
#define EE 12
#define MM 12
#define LL 512
#define OO 6
#define GOUT 768              // GRU GEMM N: [r|z|inn|hn]
#define KPAD 224              // GRU K: 12 + 192 + 20 pad
#define NKT (KPAD/32)         // 7 k-tiles
#define NJT (GOUT/16)         // 48 n-tiles

#define ROWS 30               // (t,n) rows per batch
#define HP 196                // sh_h pitch (floats)
#define LNKPU 20              // linkA pitch (uints) = 40 fp16 = 80 B
#define GRUPU 116             // gruA pitch (uints) = 232 fp16 = 464 B (29x16B: conflict-free)

typedef __attribute__((ext_vector_type(8))) _Float16 f16x8;
typedef __attribute__((ext_vector_type(4))) float f32x4;

__device__ __forceinline__ float sigmoidf_(float x) { return 1.f / (1.f + __expf(-x)); }
__device__ __forceinline__ float dot4(float4 a, float4 b) {
  return a.x*b.x + a.y*b.y + a.z*b.z + a.w*b.w;
}
__device__ __forceinline__ unsigned short f2h(float f) {
  _Float16 h = (_Float16)f;
  unsigned short s; __builtin_memcpy(&s, &h, 2); return s;
}
__device__ __forceinline__ unsigned int pack2h(float a, float b) {
  return (unsigned int)f2h(a) | ((unsigned int)f2h(b) << 16);
}

// ---------------------------------------------------------------- k_pack (GRU W, fp16)
__global__ void k_pack(const float* __restrict__ Wih, const float* __restrict__ Whh,
                       const float* __restrict__ bih, const float* __restrict__ bhh,
                       unsigned short* __restrict__ Bh, float* __restrict__ bias768)
{
  int idx = blockIdx.x * 256 + threadIdx.x;
  if (idx < GOUT) {
    int c = idx; float b;
    if (c < 384)      b = bih[c] + bhh[c];
    else if (c < 576) b = bih[c];
    else              b = bhh[c - 192];
    bias768[c] = b;
  }
  if (idx >= NJT*NKT*512) return;
  int e = idx & 7, l = (idx >> 3) & 63;
  int rem = idx >> 9, kt = rem % NKT, j = rem / NKT;
  int k = kt*32 + ((l >> 4) << 3) + e;
  int c = j*16 + (l & 15);
  float v = 0.f;
  if (k < 204) {
    if (c < 384)      v = (k < 12) ? Wih[c*MM + k] : Whh[(size_t)c*DD + (k-12)];
    else if (c < 576) v = (k < 12) ? Wih[c*MM + k] : 0.f;
    else              v = (k < 12) ? 0.f : Whh[(size_t)(c-192)*DD + (k-12)];
  }
  Bh[idx] = f2h(v);
}

// ---------------------------------------------------------------- k_pack_link (fp16)
__global__ void k_pack_link(const float* __restrict__ w1,
                            unsigned short* __restrict__ BLh)
{
  int idx = blockIdx.x * 256 + threadIdx.x;
  if (idx >= 32*512) return;
  int e = idx & 7, l = (idx >> 3) & 63, nt = idx >> 9;
  int k = ((l >> 4) << 3) + e;
  int c = nt*16 + (l & 15);
  float v = (k < 12) ? w1[c*EE + k] : 0.f;
  BLh[idx] = f2h(v);
}

// ---------------------------------------------------------------- k_fused
// One WG per batch b. Entire 2-layer network batch-local in LDS.
// GRU MFMA phase processes ONE d-tile at a time (unroll 1) so live regs
// stay ~60 (8 named acc vec4 + 4 B-frags + 2 A-frags) -> no scratch spill.
__global__ __launch_bounds__(256, 2)
void k_fused(const float* __restrict__ nr, const float* __restrict__ pos,
             const int* __restrict__ attmat,
             const unsigned short* __restrict__ BLh,
             const float* __restrict__ lb1, const float* __restrict__ lw2,
             const float* __restrict__ lb2,
             const float* __restrict__ msg_Wh, const float* __restrict__ msg_We,
             const float* __restrict__ msg_b,
             const unsigned short* __restrict__ Bh, const float* __restrict__ bias768,
             const float* __restrict__ conv1_w, const float* __restrict__ conv1_b,
             const float* __restrict__ conv2_w, const float* __restrict__ conv2_b,
             float* __restrict__ out)
{
  __shared__ __align__(16) float sh_h[ROWS][HP];        // 23520 B, fp32 node state
  __shared__ __align__(16) float sh_e[180][EE];         // 8640 B, original edge feats
  __shared__ __align__(16) float sh_m[180][MM];         // 8640 B, messages
  __shared__ __align__(16) float sh_mh[ROWS][MM];       // 1440 B
  __shared__ __align__(16) float sh_msum[ROWS][MM];     // 1440 B
  __shared__ float sh_adj[192];                         // 768 B
  __shared__ __align__(16) unsigned int shA[192*LNKPU]; // 15360 B (linkA | gruA union)
  __shared__ float red[4][OO];

  const int tid = threadIdx.x;
  const int b = blockIdx.x;
  const int lane = tid & 63, wid = tid >> 6;
  const int col = lane & 15, quad = lane >> 4;

  // ---- Phase 0: h and edge features ----
  for (int i = tid; i < TT*DD*NN; i += 256) {
    int t = i / (DD*NN), rem = i % (DD*NN);
    int d = rem / NN, n = rem % NN;
    sh_h[t*NN + n][d] = nr[(size_t)b*TT*DD*NN + i];     // coalesced
  }
  for (int idx = tid; idx < 180*EE; idx += 256) {
    int e = idx / EE, c = idx % EE;
    int t = e / 36, ij = e % 36;
    int i_ = ij / NN, j_ = ij % NN;
    bool msk = (attmat[(b*TT + t)*36 + ij] == 1) && (i_ != j_);
    int srcn = (c < 6) ? i_ : j_;
    int cc   = (c < 6) ? c  : c - 6;
    sh_e[e][c] = msk ? pos[((b*TT + t)*NN + srcn)*6 + cc] : 0.f;
  }
  __syncthreads();

  for (int L = 0; L < 2; ++L) {
    // ---- link A staging: 192 rows (180 real) x 32 k, fp16 ----
    for (int idx = tid; idx < 192*16; idx += 256) {
      int r = idx >> 4, p = idx & 15;
      float a0 = 0.f, a1 = 0.f;
      if (r < 180) {
        const float* src = (L == 0) ? &sh_e[r][0] : &sh_m[r][0];
        if (2*p   < 12) a0 = src[2*p];
        if (2*p+1 < 12) a1 = src[2*p+1];
      }
      shA[r*LNKPU + p] = pack2h(a0, a1);
    }
    __syncthreads();

    // ---- link MFMA: wave owns m-tiles {wid*3..+2}; fused relu->w2->sigmoid ----
    {
      f16x8 am[3];
      #pragma unroll
      for (int mtl = 0; mtl < 3; ++mtl)
        am[mtl] = *(const f16x8*)((const char*)shA
                    + ((wid*3 + mtl)*16 + col)*(LNKPU*4) + quad*16);
      float s[3][4];
      #pragma unroll
      for (int mtl = 0; mtl < 3; ++mtl)
        #pragma unroll
        for (int q = 0; q < 4; ++q) s[mtl][q] = 0.f;
      for (int nt = 0; nt < 32; ++nt) {
        f16x8 bh = *(const f16x8*)(BLh + nt*512 + lane*8);
        float b1v = lb1[nt*16 + col];
        float w2v = lw2[nt*16 + col];
        #pragma unroll
        for (int mtl = 0; mtl < 3; ++mtl) {
          f32x4 acc = (f32x4)0.f;
          acc = __builtin_amdgcn_mfma_f32_16x16x32_f16(am[mtl], bh, acc, 0, 0, 0);
          #pragma unroll
          for (int q = 0; q < 4; ++q)
            s[mtl][q] += w2v * fmaxf(acc[q] + b1v, 0.f);
        }
      }
      #pragma unroll
      for (int mtl = 0; mtl < 3; ++mtl)
        #pragma unroll
        for (int q = 0; q < 4; ++q) {
          float v = s[mtl][q];
          v += __shfl_xor(v, 1); v += __shfl_xor(v, 2);
          v += __shfl_xor(v, 4); v += __shfl_xor(v, 8);
          s[mtl][q] = v;
        }
      if (col == 0) {
        float b2 = lb2[0];
        #pragma unroll
        for (int mtl = 0; mtl < 3; ++mtl)
          #pragma unroll
          for (int q = 0; q < 4; ++q)
            sh_adj[wid*48 + mtl*16 + quad*4 + q] = sigmoidf_(s[mtl][q] + b2);
      }
    }
    __syncthreads();

    // ---- mh[r][o] = msg_b[o] + Wh[o,:] . h[r,:] ----
    for (int idx = tid; idx < ROWS*MM; idx += 256) {
      int r = idx / MM, o = idx % MM;
      const float4* wrow = (const float4*)(msg_Wh + (size_t)o*DD);
      const float4* hrow = (const float4*)&sh_h[r][0];
      float acc = msg_b[o];
      #pragma unroll 8
      for (int d4 = 0; d4 < DD/4; ++d4) acc += dot4(wrow[d4], hrow[d4]);
      sh_mh[r][o] = acc;
    }
    __syncthreads();

    // ---- m = adj * relu(mh_j + We.e) ----
    for (int idx = tid; idx < 180*MM; idx += 256) {
      int e = idx / MM, o = idx % MM;
      int t = e / 36, j_ = e % NN;
      const float4* we = (const float4*)(msg_We + o*EE);
      const float4* ev = (const float4*)&sh_e[e][0];
      float me = dot4(we[0],ev[0]) + dot4(we[1],ev[1]) + dot4(we[2],ev[2]);
      sh_m[e][o] = sh_adj[e] * fmaxf(sh_mh[t*NN + j_][o] + me, 0.f);
    }
    __syncthreads();

    // ---- msum[r=t*6+i][o] = sum_j m[t*36+i*6+j][o] ----
    for (int idx = tid; idx < ROWS*MM; idx += 256) {
      int r = idx / MM, o = idx % MM;
      int t = r / NN, i_ = r % NN;
      float s = 0.f;
      #pragma unroll
      for (int j = 0; j < NN; ++j) s += sh_m[t*36 + i_*NN + j][o];
      sh_msum[r][o] = s;
    }
    __syncthreads();

    // ---- GRU A staging: 32 rows x 224 k, fp16 (aliases linkA) ----
    for (int idx = tid; idx < 32*(KPAD/2); idx += 256) {
      int r = idx / (KPAD/2), kp = idx % (KPAD/2);
      int k0 = 2*kp, k1 = k0 + 1;
      float a0 = 0.f, a1 = 0.f;
      if (r < ROWS) {
        a0 = (k0 < 12) ? sh_msum[r][k0] : (k0 < 204 ? sh_h[r][k0-12] : 0.f);
        a1 = (k1 < 12) ? sh_msum[r][k1] : (k1 < 204 ? sh_h[r][k1-12] : 0.f);
      }
      shA[r*GRUPU + kp] = pack2h(a0, a1);
    }
    __syncthreads();

    // ---- GRU MFMA [32x224]x[224x768]; ONE d-tile at a time (low reg pressure).
    // inn gate B is zero for k>=12 -> only kt==0 contributes.
    {
      const char* ahb = (const char*)shA + col*(GRUPU*4) + quad*16;
      #pragma unroll 1
      for (int i = 0; i < 3; ++i) {
        const int jR = wid*3 + i;            // r gate n-tile
        const int jZ = 12 + wid*3 + i;       // z
        const int jI = 24 + wid*3 + i;       // inn
        const int jH = 36 + wid*3 + i;       // hn
        f32x4 aR0 = (f32x4)0.f, aR1 = (f32x4)0.f;
        f32x4 aZ0 = (f32x4)0.f, aZ1 = (f32x4)0.f;
        f32x4 aI0 = (f32x4)0.f, aI1 = (f32x4)0.f;
        f32x4 aH0 = (f32x4)0.f, aH1 = (f32x4)0.f;
        #pragma unroll
        for (int kt = 0; kt < NKT; ++kt) {
          f16x8 ah0 = *(const f16x8*)(ahb + kt*64);
          f16x8 ah1 = *(const f16x8*)(ahb + 16*(GRUPU*4) + kt*64);
          f16x8 bR = *(const f16x8*)(Bh + (((size_t)(jR*NKT + kt)) << 9) + lane*8);
          f16x8 bZ = *(const f16x8*)(Bh + (((size_t)(jZ*NKT + kt)) << 9) + lane*8);
          f16x8 bH = *(const f16x8*)(Bh + (((size_t)(jH*NKT + kt)) << 9) + lane*8);
          aR0 = __builtin_amdgcn_mfma_f32_16x16x32_f16(ah0, bR, aR0, 0, 0, 0);
          aR1 = __builtin_amdgcn_mfma_f32_16x16x32_f16(ah1, bR, aR1, 0, 0, 0);
          aZ0 = __builtin_amdgcn_mfma_f32_16x16x32_f16(ah0, bZ, aZ0, 0, 0, 0);
          aZ1 = __builtin_amdgcn_mfma_f32_16x16x32_f16(ah1, bZ, aZ1, 0, 0, 0);
          aH0 = __builtin_amdgcn_mfma_f32_16x16x32_f16(ah0, bH, aH0, 0, 0, 0);
          aH1 = __builtin_amdgcn_mfma_f32_16x16x32_f16(ah1, bH, aH1, 0, 0, 0);
          if (kt == 0) {
            f16x8 bI = *(const f16x8*)(Bh + (((size_t)(jI*NKT)) << 9) + lane*8);
            aI0 = __builtin_amdgcn_mfma_f32_16x16x32_f16(ah0, bI, aI0, 0, 0, 0);
            aI1 = __builtin_amdgcn_mfma_f32_16x16x32_f16(ah1, bI, aI1, 0, 0, 0);
          }
        }
        // epilogue for this d-tile
        const int d = (wid*3 + i)*16 + col;
        const float bR_ = bias768[d],       bZ_ = bias768[192 + d];
        const float bI_ = bias768[384 + d], bH_ = bias768[576 + d];
        #pragma unroll
        for (int q = 0; q < 4; ++q) {
          const int g0 = quad*4 + q;        // rows 0..15: always < ROWS
          float r_ = sigmoidf_(aR0[q] + bR_);
          float z_ = sigmoidf_(aZ0[q] + bZ_);
          float n_ = tanhf(aI0[q] + bI_ + r_*(aH0[q] + bH_));
          float hold = sh_h[g0][d];
          sh_h[g0][d] = (1.f - z_)*n_ + z_*hold;
        }
        #pragma unroll
        for (int q = 0; q < 4; ++q) {
          const int g1 = 16 + quad*4 + q;   // rows 16..31: guard < 30
          if (g1 < ROWS) {
            float r_ = sigmoidf_(aR1[q] + bR_);
            float z_ = sigmoidf_(aZ1[q] + bZ_);
            float n_ = tanhf(aI1[q] + bI_ + r_*(aH1[q] + bH_));
            float hold = sh_h[g1][d];
            sh_h[g1][d] = (1.f - z_)*n_ + z_*hold;
          }
        }
      }
    }
    __syncthreads();
  }

  // ---- conv: out[b,:] = conv2( relu( conv1(h) + b1 ) ) + b2 ----
  {
    float acco[OO];
    #pragma unroll
    for (int o = 0; o < OO; ++o) acco[o] = 0.f;
    #pragma unroll
    for (int o = 0; o < OO; ++o) {
      const float* wo = conv1_w + (size_t)o*DD*TT*NN;
      for (int u = tid; u < DD*TT*NN; u += 256)
        acco[o] += wo[u] * sh_h[u % ROWS][u / ROWS];
    }
    #pragma unroll
    for (int o = 0; o < OO; ++o) {
      float v = acco[o];
      v += __shfl_xor(v, 1);  v += __shfl_xor(v, 2);  v += __shfl_xor(v, 4);
      v += __shfl_xor(v, 8);  v += __shfl_xor(v, 16); v += __shfl_xor(v, 32);
      acco[o] = v;
    }
    if (lane == 0) {
      #pragma unroll
      for (int o = 0; o < OO; ++o) red[wid][o] = acco[o];
    }
    __syncthreads();
    if (tid == 0) {
      float y[OO];
      #pragma unroll
      for (int o = 0; o < OO; ++o) {
        float s = conv1_b[o] + red[0][o] + red[1][o] + red[2][o] + red[3][o];
        y[o] = fmaxf(s, 0.f);
      }
      #pragma unroll
      for (int q = 0; q < OO; ++q) {
        float s = conv2_b[q];
        #pragma unroll
        for (int o = 0; o < OO; ++o) s += conv2_w[q*OO + o] * y[o];
        out[b*OO + q] = s;
      }
    }
  }
}

// ---------------------------------------------------------------- launch
extern "C" void kernel_launch(void* const* d_in, const int* in_sizes, int n_in,
                              void* d_out, int out_size, void* d_ws, size_t ws_size,
                              hipStream_t stream) {
  const float* node_resnet = (const float*)d_in[0];
  const float* pos      = (const float*)d_in[1];
  const int*   attmat   = (const int*)  d_in[2];
  const float* link_w1  = (const float*)d_in[3];
  const float* link_b1  = (const float*)d_in[4];
  const float* link_w2  = (const float*)d_in[5];
  const float* link_b2  = (const float*)d_in[6];
  const float* msg_Wh   = (const float*)d_in[7];
  const float* msg_We   = (const float*)d_in[8];
  const float* msg_b    = (const float*)d_in[9];
  const float* gru_Wih  = (const float*)d_in[10];
  const float* gru_Whh  = (const float*)d_in[11];
  const float* gru_bih  = (const float*)d_in[12];
  const float* gru_bhh  = (const float*)d_in[13];
  const float* conv1_w  = (const float*)d_in[14];
  const float* conv1_b  = (const float*)d_in[15];
  const float* conv2_w  = (const float*)d_in[16];
  const float* conv2_b  = (const float*)d_in[17];
  float* out = (float*)d_out;

  // ws layout: bias768 | Bh(fp16) | BLh(fp16)   (~0.4 MB)
  float* bias = (float*)d_ws;
  unsigned short* Bh  = (unsigned short*)(bias + GOUT);
  unsigned short* BLh = Bh + (size_t)NJT*NKT*512;

  k_pack<<<(NJT*NKT*512 + 255)/256, 256, 0, stream>>>(gru_Wih, gru_Whh,
      gru_bih, gru_bhh, Bh, bias);
  k_pack_link<<<(32*512 + 255)/256, 256, 0, stream>>>(link_w1, BLh);
  k_fused<<<NB, 256, 0, stream>>>(node_resnet, pos, attmat,
      BLh, link_b1, link_w2, link_b2,
      msg_Wh, msg_We, msg_b,
      Bh, bias,
      conv1_w, conv1_b, conv2_w, conv2_b, out);
}